// Round 9
// baseline (351.776 us; speedup 1.0000x reference)
//
#include <hip/hip_runtime.h>
#include <hip/hip_bf16.h>

using short8 = __attribute__((ext_vector_type(8))) short;
using s16x4  = __attribute__((ext_vector_type(4))) short;
using f32x4  = __attribute__((ext_vector_type(4))) float;

#define HW 4096
#define CC 128
#define DH 32
#define NH 4

__device__ inline float bf2f(unsigned short u) {
    unsigned int x = ((unsigned int)u) << 16;
    return __builtin_bit_cast(float, x);
}
__device__ inline unsigned short f2bf(float f) {
    unsigned int x = __builtin_bit_cast(unsigned int, f);
    unsigned int lsb = (x >> 16) & 1u;
    x += 0x7fffu + lsb;
    return (unsigned short)(x >> 16);
}
__device__ inline float ldf(const void* p, size_t i, bool f32) {
    return f32 ? ((const float*)p)[i] : bf2f(((const unsigned short*)p)[i]);
}

// ---------------- dtype detection (f32 vs bf16 inputs) -----------------------
__global__ void detect_kernel(const unsigned int* __restrict__ x,
                              unsigned int* __restrict__ flag) {
    int bad = 0;
    for (int t = threadIdx.x; t < 256; t += 64) {
        unsigned short lo = (unsigned short)(x[t] & 0xffffu);
        float a = fabsf(bf2f(lo));
        if (!(a >= 1e-6f && a <= 1e4f)) bad++;
    }
    for (int off = 32; off; off >>= 1) bad += __shfl_down(bad, off);
    if (threadIdx.x == 0) flag[0] = (bad > 64) ? 1u : 0u;  // 1 = f32 inputs
}

// ---------------- weight conversion -> bf16 workspace ------------------------
// Wc: qkvA[0,49152) qkvB[49152,98304) outA[98304,114688) outB[114688,131072)
//     bA[131072,131200) bB[131200,131328)
__global__ void cvt_kernel(const void* __restrict__ qA, const void* __restrict__ qB,
                           const void* __restrict__ oA, const void* __restrict__ oB,
                           const void* __restrict__ bA, const void* __restrict__ bB,
                           const unsigned int* __restrict__ flag,
                           unsigned short* __restrict__ Wc) {
    const bool f32 = flag[0] != 0;
    int i = blockIdx.x * 256 + threadIdx.x;
    if (i >= 131328) return;
    const void* s; int off;
    if      (i < 49152)  { s = qA; off = i; }
    else if (i < 98304)  { s = qB; off = i - 49152; }
    else if (i < 114688) { s = oA; off = i - 98304; }
    else if (i < 131072) { s = oB; off = i - 114688; }
    else if (i < 131200) { s = bA; off = i - 131072; }
    else                 { s = bB; off = i - 131200; }
    Wc[i] = f2bf(ldf(s, off, f32));
}

// ---------------- GroupNorm -> xn bf16 [2][4096][128] + per-group stats ------
__global__ void gn_kernel(const void* __restrict__ xA,
                          const void* __restrict__ xB,
                          const void* __restrict__ gw,
                          const void* __restrict__ gb,
                          const unsigned int* __restrict__ flag,
                          float* __restrict__ stats,
                          unsigned short* __restrict__ xn) {
    const bool f32 = flag[0] != 0;
    const int s = blockIdx.y, g = blockIdx.x;
    const void* x = s ? xB : xA;
    const int c0 = g * 8;
    const int NEL = 8 * HW;
    float sum = 0.f, sumsq = 0.f;
    for (int t = threadIdx.x; t < NEL; t += 256) {
        float v = ldf(x, (size_t)c0 * HW + t, f32);
        sum += v; sumsq += v * v;
    }
    for (int off = 32; off; off >>= 1) {
        sum   += __shfl_down(sum, off);
        sumsq += __shfl_down(sumsq, off);
    }
    __shared__ float smem[8];
    int w = threadIdx.x >> 6;
    if ((threadIdx.x & 63) == 0) { smem[w] = sum; smem[4 + w] = sumsq; }
    __syncthreads();
    if (threadIdx.x == 0) {
        float s1 = smem[0] + smem[1] + smem[2] + smem[3];
        float s2 = smem[4] + smem[5] + smem[6] + smem[7];
        float mu = s1 / NEL;
        float var = s2 / NEL - mu * mu;
        float rstd = rsqrtf(var + 1e-5f);
        smem[0] = mu; smem[1] = rstd;
        stats[(s * 16 + g) * 2]     = mu;
        stats[(s * 16 + g) * 2 + 1] = rstd;
    }
    __syncthreads();
    float mu = smem[0], rstd = smem[1];
    for (int t = threadIdx.x; t < NEL; t += 256) {
        int c = c0 + (t >> 12), p = t & (HW - 1);
        float v = ldf(x, (size_t)c * HW + p, f32);
        float v_n = (v - mu) * rstd * ldf(gw, c, f32) + ldf(gb, c, f32);
        xn[(size_t)s * HW * CC + (size_t)p * CC + c] = f2bf(v_n);
    }
}

// ---------------- KV GEMM: store K and V, both as [stream*head][seq][d] ------
__global__ void qkv_kernel(const unsigned short* __restrict__ Wc,
                           const unsigned short* __restrict__ xn,
                           unsigned short* __restrict__ Kt,
                           unsigned short* __restrict__ Vs) {
    const int z = blockIdx.z;
    const unsigned short* Wq = Wc + (size_t)z * 49152;
    const int o0 = blockIdx.x * 16;
    const int w = threadIdx.x >> 6, lane = threadIdx.x & 63;
    const int quad = lane >> 4, col = lane & 15;
    const int p0 = blockIdx.y * 64 + w * 16;
    const unsigned short* xb = xn + (size_t)z * HW * CC;
    f32x4 acc = {0.f, 0.f, 0.f, 0.f};
#pragma unroll
    for (int kc = 0; kc < 4; kc++) {
        short8 a = *(const short8*)(Wq + (size_t)(o0 + col) * CC + kc * 32 + quad * 8);
        short8 b = *(const short8*)(xb + (size_t)(p0 + col) * CC + kc * 32 + quad * 8);
        acc = __builtin_amdgcn_mfma_f32_16x16x32_bf16(a, b, acc, 0, 0, 0);
    }
#pragma unroll
    for (int r = 0; r < 4; r++) {
        int o = o0 + quad * 4 + r;
        int h = o / 96, rr = o % 96;
        int p = p0 + col;
        unsigned short vb = f2bf(acc[r]);
        if (rr >= 32 && rr < 64)
            Kt[((size_t)(z * NH + h) * HW + p) * DH + (rr - 32)] = vb;
        else if (rr >= 64)
            Vs[((size_t)(z * NH + h) * HW + p) * DH + (rr - 64)] = vb;
        // q rows recomputed inside attn_kernel
    }
}

// ---------------- Flash attention (canonical verified structure) -------------
__global__ __launch_bounds__(256) void attn_kernel(
        const unsigned short* __restrict__ Wc,
        const unsigned short* __restrict__ xn,
        const unsigned short* __restrict__ Kt_all,
        const unsigned short* __restrict__ V_all,
        unsigned short* __restrict__ OT_all) {
    const int z = blockIdx.z, h = blockIdx.y;
    const int w = threadIdx.x >> 6, lane = threadIdx.x & 63;
    const int quad = lane >> 4, col = lane & 15;
    const int zq = 1 - z;  // stream z output uses Q from stream 1-z
    const unsigned short* Kt = Kt_all + (size_t)(z * NH + h) * HW * DH;
    const unsigned short* Vs = V_all  + (size_t)(z * NH + h) * HW * DH;
    unsigned short* OT = OT_all + (size_t)z * HW * CC;

    const int i0 = blockIdx.x * 64 + w * 16;

    __shared__ __align__(16) short qlds[4][16][32];
    __shared__ __align__(16) short plds[2][4][16 * 40];

    // ---- recompute Q tile: Q[i][d] ----
    {
        const unsigned short* Wq = Wc + (size_t)zq * 49152 + (size_t)(96 * h) * CC;
        const unsigned short* xq = xn + (size_t)zq * HW * CC;
#pragma unroll
        for (int dc = 0; dc < 2; dc++) {
            f32x4 qa = {0.f, 0.f, 0.f, 0.f};
#pragma unroll
            for (int kc = 0; kc < 4; kc++) {
                short8 a = *(const short8*)(Wq + (size_t)(dc * 16 + col) * CC + kc * 32 + quad * 8);
                short8 b = *(const short8*)(xq + (size_t)(i0 + col) * CC + kc * 32 + quad * 8);
                qa = __builtin_amdgcn_mfma_f32_16x16x32_bf16(a, b, qa, 0, 0, 0);
            }
#pragma unroll
            for (int r = 0; r < 4; r++)
                qlds[w][col][dc * 16 + quad * 4 + r] = (short)f2bf(qa[r]);
        }
    }
    __syncthreads();
    short8 qf = *(const short8*)(&qlds[w][col][quad * 8]);  // A[m=col][k=quad*8+j]

    f32x4 acc0 = {0.f, 0.f, 0.f, 0.f};  // O[i=quad*4+r][d=col]
    f32x4 acc1 = {0.f, 0.f, 0.f, 0.f};  // O[i=quad*4+r][d=16+col]
    float m[4] = {-1e30f, -1e30f, -1e30f, -1e30f};
    float l[4] = {0.f, 0.f, 0.f, 0.f};
    const float scale = 0.08838834764831845f;  // 1/sqrt(128)

    for (int j0 = 0; j0 < HW; j0 += 32) {
        short8 kf0 = *(const short8*)(Kt + (size_t)(j0 + col) * DH + quad * 8);
        short8 kf1 = *(const short8*)(Kt + (size_t)(j0 + 16 + col) * DH + quad * 8);
        f32x4 zero = {0.f, 0.f, 0.f, 0.f};
        f32x4 st0 = __builtin_amdgcn_mfma_f32_16x16x32_bf16(qf, kf0, zero, 0, 0, 0);
        f32x4 st1 = __builtin_amdgcn_mfma_f32_16x16x32_bf16(qf, kf1, zero, 0, 0, 0);
        const int buf = (j0 >> 5) & 1;
        short* pw = &plds[buf][w][0];
#pragma unroll
        for (int r = 0; r < 4; r++) {
            float a0 = st0[r] * scale, a1 = st1[r] * scale;
            float tm = fmaxf(a0, a1);
#pragma unroll
            for (int mask = 1; mask < 16; mask <<= 1) tm = fmaxf(tm, __shfl_xor(tm, mask));
            float nm = fmaxf(m[r], tm);
            float alpha = __expf(m[r] - nm);
            float e0 = __expf(a0 - nm), e1 = __expf(a1 - nm);
            float rs = e0 + e1;
#pragma unroll
            for (int mask = 1; mask < 16; mask <<= 1) rs += __shfl_xor(rs, mask);
            l[r] = l[r] * alpha + rs;
            m[r] = nm;
            acc0[r] *= alpha; acc1[r] *= alpha;
            pw[(quad * 4 + r) * 40 + col]      = (short)f2bf(e0);
            pw[(quad * 4 + r) * 40 + 16 + col] = (short)f2bf(e1);
        }
        __syncthreads();
        short8 pf = *(const short8*)(pw + col * 40 + quad * 8);  // A[m=col][k]
        short8 vb0, vb1;
#pragma unroll
        for (int jj = 0; jj < 8; jj++) {
            vb0[jj] = (short)Vs[(size_t)(j0 + quad * 8 + jj) * DH + col];
            vb1[jj] = (short)Vs[(size_t)(j0 + quad * 8 + jj) * DH + 16 + col];
        }
        acc0 = __builtin_amdgcn_mfma_f32_16x16x32_bf16(pf, vb0, acc0, 0, 0, 0);
        acc1 = __builtin_amdgcn_mfma_f32_16x16x32_bf16(pf, vb1, acc1, 0, 0, 0);
    }
#pragma unroll
    for (int r = 0; r < 4; r++) {
        float inv = 1.0f / l[r];
        int i = i0 + quad * 4 + r;
        OT[(size_t)i * CC + h * DH + col]      = f2bf(acc0[r] * inv);
        OT[(size_t)i * CC + h * DH + 16 + col] = f2bf(acc1[r] * inv);
    }
}

// ---------------- Out proj + bias + f32 residual -> FLOAT32 output -----------
__global__ void proj_kernel(const unsigned short* __restrict__ Wc,
                            const unsigned short* __restrict__ OT_all,
                            const void* __restrict__ xA,
                            const void* __restrict__ xB,
                            const void* __restrict__ gw,
                            const void* __restrict__ gb,
                            const unsigned int* __restrict__ flag,
                            const float* __restrict__ stats,
                            float* __restrict__ out) {
    const bool f32 = flag[0] != 0;
    const int z = blockIdx.z;
    const unsigned short* Wp = Wc + 98304 + (size_t)z * 16384;
    const unsigned short* bp = Wc + 131072 + (size_t)z * 128;
    const void* xz = z ? xB : xA;
    const int o0 = blockIdx.x * 16;
    const int w = threadIdx.x >> 6, lane = threadIdx.x & 63;
    const int quad = lane >> 4, col = lane & 15;
    const int p0 = blockIdx.y * 64 + w * 16;
    const unsigned short* ob = OT_all + (size_t)z * HW * CC;
    f32x4 acc = {0.f, 0.f, 0.f, 0.f};
#pragma unroll
    for (int kc = 0; kc < 4; kc++) {
        short8 a = *(const short8*)(Wp + (size_t)(o0 + col) * CC + kc * 32 + quad * 8);
        short8 b = *(const short8*)(ob + (size_t)(p0 + col) * CC + kc * 32 + quad * 8);
        acc = __builtin_amdgcn_mfma_f32_16x16x32_bf16(a, b, acc, 0, 0, 0);
    }
    const int p = p0 + col;
#pragma unroll
    for (int r = 0; r < 4; r++) {
        int o = o0 + quad * 4 + r;
        int g = o >> 3;
        float mu   = stats[(z * 16 + g) * 2];
        float rstd = stats[(z * 16 + g) * 2 + 1];
        float xv = ldf(xz, (size_t)o * HW + p, f32);
        float res = (xv - mu) * rstd * ldf(gw, o, f32) + ldf(gb, o, f32);
        // d_out is FLOAT32 (reference output dtype) — this was the 6.8125 bug
        out[(size_t)z * CC * HW + (size_t)o * HW + p] = acc[r] + bf2f(bp[o]) + res;
    }
}

extern "C" void kernel_launch(void* const* d_in, const int* in_sizes, int n_in,
                              void* d_out, int out_size, void* d_ws, size_t ws_size,
                              hipStream_t stream) {
    (void)in_sizes; (void)n_in; (void)out_size; (void)ws_size;
    const void* xA    = d_in[0];
    const void* xB    = d_in[1];
    const void* gnw   = d_in[2];
    const void* gnb   = d_in[3];
    const void* qkvAw = d_in[4];
    const void* outAw = d_in[5];
    const void* outAb = d_in[6];
    const void* qkvBw = d_in[7];
    const void* outBw = d_in[8];
    const void* outBb = d_in[9];

    // workspace: 9 MB total
    char* ws = (char*)d_ws;
    unsigned int*   flag  = (unsigned int*)ws;                  // 4 B
    float*          stats = (float*)(ws + 64);                  // 256 B [2][16][2]
    unsigned short* Wc    = (unsigned short*)(ws + 4096);       // 257 KB
    unsigned short* Kt    = (unsigned short*)(ws + (1u << 20)); // 2 MB [2][4][4096][32]
    unsigned short* Vs    = (unsigned short*)(ws + (3u << 20)); // 2 MB [2][4][4096][32]
    unsigned short* OT    = (unsigned short*)(ws + (5u << 20)); // 2 MB [2][4096][128]
    unsigned short* xn    = (unsigned short*)(ws + (7u << 20)); // 2 MB [2][4096][128]

    detect_kernel<<<1, 64, 0, stream>>>((const unsigned int*)xA, flag);
    cvt_kernel<<<513, 256, 0, stream>>>(qkvAw, qkvBw, outAw, outBw, outAb, outBb,
                                        flag, Wc);
    gn_kernel<<<dim3(16, 2), 256, 0, stream>>>(xA, xB, gnw, gnb, flag, stats, xn);
    qkv_kernel<<<dim3(24, 64, 2), 256, 0, stream>>>(Wc, xn, Kt, Vs);
    attn_kernel<<<dim3(64, 4, 2), 256, 0, stream>>>(Wc, xn, Kt, Vs, OT);
    proj_kernel<<<dim3(8, 64, 2), 256, 0, stream>>>(Wc, OT, xA, xB, gnw, gnb,
                                                    flag, stats, (float*)d_out);
}

// Round 10
// 321.612 us; speedup vs baseline: 1.0938x; 1.0938x over previous
//
#include <hip/hip_runtime.h>
#include <hip/hip_bf16.h>

using short8 = __attribute__((ext_vector_type(8))) short;
using s16x4  = __attribute__((ext_vector_type(4))) short;
using f32x4  = __attribute__((ext_vector_type(4))) float;

#define HW 4096
#define CC 128
#define DH 32
#define NH 4

__device__ inline float bf2f(unsigned short u) {
    unsigned int x = ((unsigned int)u) << 16;
    return __builtin_bit_cast(float, x);
}
__device__ inline unsigned short f2bf(float f) {
    unsigned int x = __builtin_bit_cast(unsigned int, f);
    unsigned int lsb = (x >> 16) & 1u;
    x += 0x7fffu + lsb;
    return (unsigned short)(x >> 16);
}
__device__ inline float ldf(const void* p, size_t i, bool f32) {
    return f32 ? ((const float*)p)[i] : bf2f(((const unsigned short*)p)[i]);
}
__device__ inline float fexp2(float x) { return __builtin_amdgcn_exp2f(x); }

// ---------------- dtype detection (f32 vs bf16 inputs) -----------------------
__global__ void detect_kernel(const unsigned int* __restrict__ x,
                              unsigned int* __restrict__ flag) {
    int bad = 0;
    for (int t = threadIdx.x; t < 256; t += 64) {
        unsigned short lo = (unsigned short)(x[t] & 0xffffu);
        float a = fabsf(bf2f(lo));
        if (!(a >= 1e-6f && a <= 1e4f)) bad++;
    }
    for (int off = 32; off; off >>= 1) bad += __shfl_down(bad, off);
    if (threadIdx.x == 0) flag[0] = (bad > 64) ? 1u : 0u;  // 1 = f32 inputs
}

// ---------------- weight conversion -> bf16 workspace ------------------------
// Wc: qkvA[0,49152) qkvB[49152,98304) outA[98304,114688) outB[114688,131072)
//     bA[131072,131200) bB[131200,131328)
__global__ void cvt_kernel(const void* __restrict__ qA, const void* __restrict__ qB,
                           const void* __restrict__ oA, const void* __restrict__ oB,
                           const void* __restrict__ bA, const void* __restrict__ bB,
                           const unsigned int* __restrict__ flag,
                           unsigned short* __restrict__ Wc) {
    const bool f32 = flag[0] != 0;
    int i = blockIdx.x * 256 + threadIdx.x;
    if (i >= 131328) return;
    const void* s; int off;
    if      (i < 49152)  { s = qA; off = i; }
    else if (i < 98304)  { s = qB; off = i - 49152; }
    else if (i < 114688) { s = oA; off = i - 98304; }
    else if (i < 131072) { s = oB; off = i - 114688; }
    else if (i < 131200) { s = bA; off = i - 131072; }
    else                 { s = bB; off = i - 131200; }
    Wc[i] = f2bf(ldf(s, off, f32));
}

// ---------------- GroupNorm -> xn bf16 [2][4096][128] + per-group stats ------
__global__ void gn_kernel(const void* __restrict__ xA,
                          const void* __restrict__ xB,
                          const void* __restrict__ gw,
                          const void* __restrict__ gb,
                          const unsigned int* __restrict__ flag,
                          float* __restrict__ stats,
                          unsigned short* __restrict__ xn) {
    const bool f32 = flag[0] != 0;
    const int s = blockIdx.y, g = blockIdx.x;
    const void* x = s ? xB : xA;
    const int c0 = g * 8;
    const int NEL = 8 * HW;
    float sum = 0.f, sumsq = 0.f;
    for (int t = threadIdx.x; t < NEL; t += 256) {
        float v = ldf(x, (size_t)c0 * HW + t, f32);
        sum += v; sumsq += v * v;
    }
    for (int off = 32; off; off >>= 1) {
        sum   += __shfl_down(sum, off);
        sumsq += __shfl_down(sumsq, off);
    }
    __shared__ float smem[8];
    int w = threadIdx.x >> 6;
    if ((threadIdx.x & 63) == 0) { smem[w] = sum; smem[4 + w] = sumsq; }
    __syncthreads();
    if (threadIdx.x == 0) {
        float s1 = smem[0] + smem[1] + smem[2] + smem[3];
        float s2 = smem[4] + smem[5] + smem[6] + smem[7];
        float mu = s1 / NEL;
        float var = s2 / NEL - mu * mu;
        float rstd = rsqrtf(var + 1e-5f);
        smem[0] = mu; smem[1] = rstd;
        stats[(s * 16 + g) * 2]     = mu;
        stats[(s * 16 + g) * 2 + 1] = rstd;
    }
    __syncthreads();
    float mu = smem[0], rstd = smem[1];
    for (int t = threadIdx.x; t < NEL; t += 256) {
        int c = c0 + (t >> 12), p = t & (HW - 1);
        float v = ldf(x, (size_t)c * HW + p, f32);
        float v_n = (v - mu) * rstd * ldf(gw, c, f32) + ldf(gb, c, f32);
        xn[(size_t)s * HW * CC + (size_t)p * CC + c] = f2bf(v_n);
    }
}

// ---------------- KV GEMM: K as [z*NH+h][seq][d], V as [z*NH+h][d][seq] ------
__global__ void qkv_kernel(const unsigned short* __restrict__ Wc,
                           const unsigned short* __restrict__ xn,
                           unsigned short* __restrict__ Kt,
                           unsigned short* __restrict__ VT) {
    const int z = blockIdx.z;
    const unsigned short* Wq = Wc + (size_t)z * 49152;
    const int o0 = blockIdx.x * 16;
    const int w = threadIdx.x >> 6, lane = threadIdx.x & 63;
    const int quad = lane >> 4, col = lane & 15;
    const int p0 = blockIdx.y * 64 + w * 16;
    const unsigned short* xb = xn + (size_t)z * HW * CC;
    f32x4 acc = {0.f, 0.f, 0.f, 0.f};
#pragma unroll
    for (int kc = 0; kc < 4; kc++) {
        short8 a = *(const short8*)(Wq + (size_t)(o0 + col) * CC + kc * 32 + quad * 8);
        short8 b = *(const short8*)(xb + (size_t)(p0 + col) * CC + kc * 32 + quad * 8);
        acc = __builtin_amdgcn_mfma_f32_16x16x32_bf16(a, b, acc, 0, 0, 0);
    }
#pragma unroll
    for (int r = 0; r < 4; r++) {
        int o = o0 + quad * 4 + r;
        int h = o / 96, rr = o % 96;
        int p = p0 + col;
        unsigned short vb = f2bf(acc[r]);
        if (rr >= 32 && rr < 64)
            Kt[((size_t)(z * NH + h) * HW + p) * DH + (rr - 32)] = vb;
        else if (rr >= 64)
            VT[((size_t)(z * NH + h) * DH + (rr - 64)) * HW + p] = vb;
        // q rows recomputed inside attn_kernel
    }
}

// ---------------- Flash attention: S^T formulation, zero-LDS inner loop ------
// S^T = K·Q^T (A=K rows, B=Q): C-layout st[X][r] = S[j0+X*16+quad*4+r][i0+col].
// P^T stays in registers as the PV B-operand with k-slot meaning
// g(quad,jj) = (jj<4 ? quad*4+jj : 16+quad*4+jj-4); the V^T A-fragments are
// loaded with the SAME permutation, so the contraction is exact.
// Output O^T in C-layout: acc0[r] = O[d=quad*4+r][i0+col], acc1: d+16.
__global__ __launch_bounds__(256) void attn_kernel(
        const unsigned short* __restrict__ Wc,
        const unsigned short* __restrict__ xn,
        const unsigned short* __restrict__ Kt_all,
        const unsigned short* __restrict__ VT_all,
        unsigned short* __restrict__ OT_all) {
    const int z = blockIdx.z, h = blockIdx.y;
    const int w = threadIdx.x >> 6, lane = threadIdx.x & 63;
    const int quad = lane >> 4, col = lane & 15;
    const int zq = 1 - z;  // stream z output uses Q from stream 1-z
    const unsigned short* Kt = Kt_all + (size_t)(z * NH + h) * HW * DH;
    const unsigned short* VT = VT_all + (size_t)(z * NH + h) * DH * HW;
    unsigned short* OT = OT_all + (size_t)z * HW * CC;

    const int i0 = blockIdx.x * 64 + w * 16;

    __shared__ __align__(16) short qlds[4][16][32];

    // ---- recompute Q tile: Q[i][d] (verified GEMM pattern) ----
    {
        const unsigned short* Wq = Wc + (size_t)zq * 49152 + (size_t)(96 * h) * CC;
        const unsigned short* xq = xn + (size_t)zq * HW * CC;
#pragma unroll
        for (int dc = 0; dc < 2; dc++) {
            f32x4 qa = {0.f, 0.f, 0.f, 0.f};
#pragma unroll
            for (int kc = 0; kc < 4; kc++) {
                short8 a = *(const short8*)(Wq + (size_t)(dc * 16 + col) * CC + kc * 32 + quad * 8);
                short8 b = *(const short8*)(xq + (size_t)(i0 + col) * CC + kc * 32 + quad * 8);
                qa = __builtin_amdgcn_mfma_f32_16x16x32_bf16(a, b, qa, 0, 0, 0);
            }
#pragma unroll
            for (int r = 0; r < 4; r++)
                qlds[w][col][dc * 16 + quad * 4 + r] = (short)f2bf(qa[r]);
        }
    }
    __syncthreads();
    // B-operand of S^T: B[k=d=quad*8+jj][n=i_local=col] = Q[i0+col][d]
    short8 qf = *(const short8*)(&qlds[w][col][quad * 8]);

    f32x4 acc0 = {0.f, 0.f, 0.f, 0.f};  // O[d=quad*4+r][i=i0+col]
    f32x4 acc1 = {0.f, 0.f, 0.f, 0.f};  // O[d=16+quad*4+r][i=i0+col]
    float mi = -1e30f, li = 0.f;        // per-lane state for i = i0+col (log2 units)
    const float kscale = 0.12751569782174257f;  // (1/sqrt(128)) * log2(e)

    for (int j0 = 0; j0 < HW; j0 += 64) {
        f32x4 st[4];
#pragma unroll
        for (int X = 0; X < 4; X++) {
            short8 kf = *(const short8*)(Kt + (size_t)(j0 + X * 16 + col) * DH + quad * 8);
            f32x4 zero = {0.f, 0.f, 0.f, 0.f};
            st[X] = __builtin_amdgcn_mfma_f32_16x16x32_bf16(kf, qf, zero, 0, 0, 0);
        }
        float a[16];
#pragma unroll
        for (int X = 0; X < 4; X++)
#pragma unroll
            for (int r = 0; r < 4; r++) a[X * 4 + r] = st[X][r] * kscale;
        float tm = a[0];
#pragma unroll
        for (int t = 1; t < 16; t++) tm = fmaxf(tm, a[t]);
        tm = fmaxf(tm, __shfl_xor(tm, 16));
        tm = fmaxf(tm, __shfl_xor(tm, 32));
        float nm = fmaxf(mi, tm);
        float alpha = fexp2(mi - nm);
        float e[16], rs = 0.f;
#pragma unroll
        for (int t = 0; t < 16; t++) { e[t] = fexp2(a[t] - nm); rs += e[t]; }
        rs += __shfl_xor(rs, 16);
        rs += __shfl_xor(rs, 32);
        li = li * alpha + rs;
        mi = nm;
        // P^T B-operands: pb0 covers j0..j0+31 (st0,st1), pb1: j0+32..j0+63
        short8 pb0, pb1;
#pragma unroll
        for (int t = 0; t < 4; t++) {
            pb0[t]     = (short)f2bf(e[t]);       // j_local = quad*4+t
            pb0[4 + t] = (short)f2bf(e[4 + t]);   // j_local = 16+quad*4+t
            pb1[t]     = (short)f2bf(e[8 + t]);   // j_local = 32+quad*4+t
            pb1[4 + t] = (short)f2bf(e[12 + t]);  // j_local = 48+quad*4+t
        }
#pragma unroll
        for (int r = 0; r < 4; r++) { acc0[r] *= alpha; acc1[r] *= alpha; }
        // V^T A-fragments with matching k-permutation: reg jj<4 -> j0+quad*4+jj,
        // jj>=4 -> j0+16+quad*4+(jj-4); sub-tile 1 adds 32.
        const unsigned short* v0 = VT + (size_t)col * HW + j0 + quad * 4;        // d=col
        const unsigned short* v1 = VT + (size_t)(16 + col) * HW + j0 + quad * 4; // d=16+col
        s16x4 l00 = *(const s16x4*)(v0);       s16x4 h00 = *(const s16x4*)(v0 + 16);
        s16x4 l01 = *(const s16x4*)(v0 + 32);  s16x4 h01 = *(const s16x4*)(v0 + 48);
        s16x4 l10 = *(const s16x4*)(v1);       s16x4 h10 = *(const s16x4*)(v1 + 16);
        s16x4 l11 = *(const s16x4*)(v1 + 32);  s16x4 h11 = *(const s16x4*)(v1 + 48);
        short8 va;
#pragma unroll
        for (int t = 0; t < 4; t++) { va[t] = l00[t]; va[4 + t] = h00[t]; }
        acc0 = __builtin_amdgcn_mfma_f32_16x16x32_bf16(va, pb0, acc0, 0, 0, 0);
#pragma unroll
        for (int t = 0; t < 4; t++) { va[t] = l10[t]; va[4 + t] = h10[t]; }
        acc1 = __builtin_amdgcn_mfma_f32_16x16x32_bf16(va, pb0, acc1, 0, 0, 0);
#pragma unroll
        for (int t = 0; t < 4; t++) { va[t] = l01[t]; va[4 + t] = h01[t]; }
        acc0 = __builtin_amdgcn_mfma_f32_16x16x32_bf16(va, pb1, acc0, 0, 0, 0);
#pragma unroll
        for (int t = 0; t < 4; t++) { va[t] = l11[t]; va[4 + t] = h11[t]; }
        acc1 = __builtin_amdgcn_mfma_f32_16x16x32_bf16(va, pb1, acc1, 0, 0, 0);
    }
    float inv = 1.0f / li;
    s16x4 o0, o1;
#pragma unroll
    for (int r = 0; r < 4; r++) {
        o0[r] = (short)f2bf(acc0[r] * inv);
        o1[r] = (short)f2bf(acc1[r] * inv);
    }
    *(s16x4*)(OT + (size_t)(i0 + col) * CC + h * DH + quad * 4)      = o0;
    *(s16x4*)(OT + (size_t)(i0 + col) * CC + h * DH + 16 + quad * 4) = o1;
}

// ---------------- Out proj + bias + f32 residual -> FLOAT32 output -----------
__global__ void proj_kernel(const unsigned short* __restrict__ Wc,
                            const unsigned short* __restrict__ OT_all,
                            const void* __restrict__ xA,
                            const void* __restrict__ xB,
                            const void* __restrict__ gw,
                            const void* __restrict__ gb,
                            const unsigned int* __restrict__ flag,
                            const float* __restrict__ stats,
                            float* __restrict__ out) {
    const bool f32 = flag[0] != 0;
    const int z = blockIdx.z;
    const unsigned short* Wp = Wc + 98304 + (size_t)z * 16384;
    const unsigned short* bp = Wc + 131072 + (size_t)z * 128;
    const void* xz = z ? xB : xA;
    const int o0 = blockIdx.x * 16;
    const int w = threadIdx.x >> 6, lane = threadIdx.x & 63;
    const int quad = lane >> 4, col = lane & 15;
    const int p0 = blockIdx.y * 64 + w * 16;
    const unsigned short* ob = OT_all + (size_t)z * HW * CC;
    f32x4 acc = {0.f, 0.f, 0.f, 0.f};
#pragma unroll
    for (int kc = 0; kc < 4; kc++) {
        short8 a = *(const short8*)(Wp + (size_t)(o0 + col) * CC + kc * 32 + quad * 8);
        short8 b = *(const short8*)(ob + (size_t)(p0 + col) * CC + kc * 32 + quad * 8);
        acc = __builtin_amdgcn_mfma_f32_16x16x32_bf16(a, b, acc, 0, 0, 0);
    }
    const int p = p0 + col;
#pragma unroll
    for (int r = 0; r < 4; r++) {
        int o = o0 + quad * 4 + r;
        int g = o >> 3;
        float mu   = stats[(z * 16 + g) * 2];
        float rstd = stats[(z * 16 + g) * 2 + 1];
        float xv = ldf(xz, (size_t)o * HW + p, f32);
        float res = (xv - mu) * rstd * ldf(gw, o, f32) + ldf(gb, o, f32);
        out[(size_t)z * CC * HW + (size_t)o * HW + p] = acc[r] + bf2f(bp[o]) + res;
    }
}

extern "C" void kernel_launch(void* const* d_in, const int* in_sizes, int n_in,
                              void* d_out, int out_size, void* d_ws, size_t ws_size,
                              hipStream_t stream) {
    (void)in_sizes; (void)n_in; (void)out_size; (void)ws_size;
    const void* xA    = d_in[0];
    const void* xB    = d_in[1];
    const void* gnw   = d_in[2];
    const void* gnb   = d_in[3];
    const void* qkvAw = d_in[4];
    const void* outAw = d_in[5];
    const void* outAb = d_in[6];
    const void* qkvBw = d_in[7];
    const void* outBw = d_in[8];
    const void* outBb = d_in[9];

    // workspace: 9 MB total
    char* ws = (char*)d_ws;
    unsigned int*   flag  = (unsigned int*)ws;                  // 4 B
    float*          stats = (float*)(ws + 64);                  // 256 B [2][16][2]
    unsigned short* Wc    = (unsigned short*)(ws + 4096);       // 257 KB
    unsigned short* Kt    = (unsigned short*)(ws + (1u << 20)); // 2 MB [2][4][4096][32]
    unsigned short* VT    = (unsigned short*)(ws + (3u << 20)); // 2 MB [2][4][32][4096]
    unsigned short* OT    = (unsigned short*)(ws + (5u << 20)); // 2 MB [2][4096][128]
    unsigned short* xn    = (unsigned short*)(ws + (7u << 20)); // 2 MB [2][4096][128]

    detect_kernel<<<1, 64, 0, stream>>>((const unsigned int*)xA, flag);
    cvt_kernel<<<513, 256, 0, stream>>>(qkvAw, qkvBw, outAw, outBw, outAb, outBb,
                                        flag, Wc);
    gn_kernel<<<dim3(16, 2), 256, 0, stream>>>(xA, xB, gnw, gnb, flag, stats, xn);
    qkv_kernel<<<dim3(24, 64, 2), 256, 0, stream>>>(Wc, xn, Kt, VT);
    attn_kernel<<<dim3(64, 4, 2), 256, 0, stream>>>(Wc, xn, Kt, VT, OT);
    proj_kernel<<<dim3(8, 64, 2), 256, 0, stream>>>(Wc, OT, xA, xB, gnw, gnb,
                                                    flag, stats, (float*)d_out);
}